// Round 4
// baseline (271.607 us; speedup 1.0000x reference)
//
#include <hip/hip_runtime.h>

#define T_SEQ 2048
#define N_B   4
#define N_H   16
#define D_H   64
#define EMB   1024
#define CSC   0.18033688011f  // log2(e) / sqrt(64), folded into Q at projection

typedef __attribute__((ext_vector_type(8))) short vshort8;  // 8 bf16 (4 VGPRs)
typedef __attribute__((ext_vector_type(4))) float vfloat4;  // MFMA C/D

__device__ __forceinline__ ushort f2bf(float f) {
  union { float f; unsigned u; } v; v.f = f;
  unsigned u = v.u;
  return (ushort)((u + 0x7fffu + ((u >> 16) & 1u)) >> 16);  // RNE
}
__device__ __forceinline__ unsigned pk2bf(float a, float b) {  // [bf(a),bf(b)] in mem
  return (unsigned)f2bf(a) | ((unsigned)f2bf(b) << 16);
}
__device__ __forceinline__ float bf2f(ushort b) {
  union { unsigned u; float f; } v; v.u = ((unsigned)b) << 16;
  return v.f;
}
__device__ __forceinline__ float fexp2(float x) {
#if __has_builtin(__builtin_amdgcn_exp2f)
  return __builtin_amdgcn_exp2f(x);
#else
  return exp2f(x);
#endif
}
// pack hi16(lo),hi16(hi) -> [bf_trunc(lo), bf_trunc(hi)] in memory (1 v_perm)
__device__ __forceinline__ unsigned permhi(float hi, float lo) {
  union { float f; unsigned u; } a, b; a.f = hi; b.f = lo;
#if __has_builtin(__builtin_amdgcn_perm)
  return __builtin_amdgcn_perm(a.u, b.u, 0x07060302u);
#else
  return (a.u & 0xFFFF0000u) | (b.u >> 16);
#endif
}
__device__ __forceinline__ vshort8 cvt8(const float* p) {
  float4 w0 = *(const float4*)(p);
  float4 w1 = *(const float4*)(p + 4);
  vshort8 t;
  t[0] = (short)f2bf(w0.x); t[1] = (short)f2bf(w0.y);
  t[2] = (short)f2bf(w0.z); t[3] = (short)f2bf(w0.w);
  t[4] = (short)f2bf(w1.x); t[5] = (short)f2bf(w1.y);
  t[6] = (short)f2bf(w1.z); t[7] = (short)f2bf(w1.w);
  return t;
}

// Blob layout (per matrix): uint2 blob[bh][strip(128)][nt(4)][l15(16)][quad(4)]
//   Q/K: uint2 = 4 consecutive d at fixed row t/s (from swapped-MFMA C-layout)
//   V  : uint2 = 4 consecutive s at fixed d      (from normal-MFMA C-layout)

// ---------------- W pre-conversion (runs once, 1 wave) ----------------
// Wb[((m*2+kc)*4+nt)*64 + lane] : vshort8 = W[m][16nt+l15][kc*32+quad*8 .. +8]
__global__ void wconv(const float* __restrict__ Wq, const float* __restrict__ Wk,
                      const float* __restrict__ Wv, ushort* __restrict__ Wb) {
  const int lane = threadIdx.x & 63;
  const int l15  = lane & 15;
  const int quad = lane >> 4;
  const float* Ws[3] = {Wq, Wk, Wv};
#pragma unroll
  for (int m = 0; m < 3; ++m)
#pragma unroll
    for (int kc = 0; kc < 2; ++kc)
#pragma unroll
      for (int nt = 0; nt < 4; ++nt) {
        vshort8 t = cvt8(Ws[m] + (nt * 16 + l15) * D_H + kc * 32 + quad * 8);
        *(vshort8*)(&Wb[(((m * 2 + kc) * 4 + nt) * 64 + lane) * 8]) = t;
      }
}

// ---------------- QKV projection ----------------
// Wave = 16 rows (1 strip) of one head; W frags from pre-converted Wb (b128).
__global__ __launch_bounds__(256, 4) void proj_qkv(
    const float* __restrict__ x, const ushort* __restrict__ Wb,
    uint2* __restrict__ Qb, uint2* __restrict__ Kb, uint2* __restrict__ Vb) {
  const int wid  = threadIdx.x >> 6;
  const int lane = threadIdx.x & 63;
  const int l15  = lane & 15;
  const int quad = lane >> 4;
  const int gw    = blockIdx.x * 4 + wid;   // [0,8192)
  const int strip = gw >> 4;                // 16-row strip over B*T
  const int h     = gw & 15;
  const int r0    = strip * 16;
  const int b     = r0 >> 11;
  const int bh    = b * N_H + h;
  const int ts    = (r0 & (T_SEQ - 1)) >> 4;

  // x frag: lane holds x[r0+l15][h*64 + kc*32 + quad*8 + j]
  vshort8 afr[2];
  {
    const float* xp = x + (size_t)(r0 + l15) * EMB + h * D_H + quad * 8;
    afr[0] = cvt8(xp);
    afr[1] = cvt8(xp + 32);
  }

  uint2* Bs[3] = {Qb, Kb, Vb};
#pragma unroll
  for (int m = 0; m < 3; ++m) {
    vshort8 wf[2][4];
#pragma unroll
    for (int kc = 0; kc < 2; ++kc)
#pragma unroll
      for (int nt = 0; nt < 4; ++nt)
        wf[kc][nt] = *(const vshort8*)(&Wb[(((m * 2 + kc) * 4 + nt) * 64 + lane) * 8]);
    vfloat4 acc[4];
#pragma unroll
    for (int nt = 0; nt < 4; ++nt) acc[nt] = (vfloat4){0.f, 0.f, 0.f, 0.f};
#pragma unroll
    for (int kc = 0; kc < 2; ++kc)
#pragma unroll
      for (int nt = 0; nt < 4; ++nt)
        acc[nt] = (m < 2)
          ? __builtin_amdgcn_mfma_f32_16x16x32_bf16(wf[kc][nt], afr[kc], acc[nt], 0, 0, 0)
          : __builtin_amdgcn_mfma_f32_16x16x32_bf16(afr[kc], wf[kc][nt], acc[nt], 0, 0, 0);
    uint2* B = Bs[m];
#pragma unroll
    for (int nt = 0; nt < 4; ++nt) {
      vfloat4 a = acc[nt];
      if (m == 0) { a[0] *= CSC; a[1] *= CSC; a[2] *= CSC; a[3] *= CSC; }
      uint2 w;
      w.x = pk2bf(a[0], a[1]);
      w.y = pk2bf(a[2], a[3]);
      B[(((size_t)bh * 128 + ts) * 4 + nt) * 64 + l15 * 4 + quad] = w;
    }
  }
}

// ---------------- fused flash attention (no-max softmax) + V residual --------
// Wave = 64 q-rows (4 strips), block = 4 waves (256 t) of one (b,h).
// K-frags double-buffered one s-tile ahead; V-frags issued one phase ahead.
__global__ __launch_bounds__(256, 2) void attn_fused(
    const uint2* __restrict__ Qb, const uint2* __restrict__ Kb,
    const uint2* __restrict__ Vb, float* __restrict__ out) {
  __shared__ ushort Pa[4 * 1024];  // per-wave 16x64 P tile, XOR-swizzled chunks

  const int tid  = threadIdx.x;
  const int wid  = tid >> 6;
  const int lane = tid & 63;
  const int l15  = lane & 15;
  const int quad = lane >> 4;
  const int qh   = quad >> 1;
  const int q1   = quad & 1;

  // XCD swizzle: 16 consecutive per-XCD slots share a bh -> K/V stay in that L2
  const int blk  = blockIdx.x;                 // [0,512)
  const int work = (blk & 7) * 64 + (blk >> 3);
  const int bh   = work >> 3;
  const int tblk = work & 7;
  const int b = bh >> 4, h = bh & 15;
  const int tstrip0 = tblk * 16 + wid * 4;

  const size_t hb = (size_t)bh * 128;
  const int laneoff = l15 * 4 + 2 * q1;        // uint2 units

  const uint2* kbase = Kb + hb * 256 + qh * 64 + laneoff;
  const uint2* vbase = Vb + hb * 256 + qh * 256 + laneoff;

  // Q frags (B-operand of S^T): lane holds Q[t=l15][d=kc*32+quad*8+j] * CSC
  vshort8 qf[4][2];
#pragma unroll
  for (int st = 0; st < 4; ++st)
#pragma unroll
    for (int kc = 0; kc < 2; ++kc)
      qf[st][kc] = *(const vshort8*)(&Qb[((hb + tstrip0 + st) * 4 + 2 * kc + qh) * 64 + laneoff]);

  vfloat4 oacc[4][4];
  float lsum[4];
#pragma unroll
  for (int st = 0; st < 4; ++st) {
#pragma unroll
    for (int nt = 0; nt < 4; ++nt) oacc[st][nt] = (vfloat4){0.f, 0.f, 0.f, 0.f};
    lsum[st] = 0.f;
  }

  ushort* Paw = &Pa[wid * 1024];
  const int parow = l15 * 64;   // elements
  const int swz   = l15 & 7;

  auto loadK = [&](vshort8 (&kf)[4][2], int ssb) {
#pragma unroll
    for (int snt = 0; snt < 4; ++snt)
#pragma unroll
      for (int kc = 0; kc < 2; ++kc)
        kf[snt][kc] = *(const vshort8*)(kbase + (ssb + snt) * 256 + kc * 128);
  };
  auto loadV = [&](vshort8 (&vf)[2][4], int ssb) {
#pragma unroll
    for (int kc2 = 0; kc2 < 2; ++kc2)
#pragma unroll
      for (int dnt = 0; dnt < 4; ++dnt)
        vf[kc2][dnt] = *(const vshort8*)(vbase + (ssb + 2 * kc2) * 256 + dnt * 64);
  };
  auto body = [&](vshort8 (&kf)[4][2], vshort8 (&vf)[2][4]) {
#pragma unroll
    for (int st = 0; st < 4; ++st) {
      // S^T = K * Q^T : C holds (s = 16nt+4quad+r, t = l15)
      vfloat4 sacc[4];
#pragma unroll
      for (int nt = 0; nt < 4; ++nt) sacc[nt] = (vfloat4){0.f, 0.f, 0.f, 0.f};
#pragma unroll
      for (int kc = 0; kc < 2; ++kc)
#pragma unroll
        for (int nt = 0; nt < 4; ++nt)
          sacc[nt] = __builtin_amdgcn_mfma_f32_16x16x32_bf16(kf[nt][kc], qf[st][kc], sacc[nt], 0, 0, 0);

      // no-max softmax: p = exp2(sacc); per-lane partial l; P -> Pa (swizzled)
      float ls = 0.f;
#pragma unroll
      for (int nt = 0; nt < 4; ++nt) {
        const float p0 = fexp2(sacc[nt][0]);
        const float p1 = fexp2(sacc[nt][1]);
        const float p2 = fexp2(sacc[nt][2]);
        const float p3 = fexp2(sacc[nt][3]);
        ls += (p0 + p1) + (p2 + p3);
        uint2 w;
        w.x = permhi(p1, p0);
        w.y = permhi(p3, p2);
        *(uint2*)(&Paw[parow + (((2 * nt + qh) ^ swz) << 3) + 4 * q1]) = w;
      }
      lsum[st] += ls;

      // O += P * V : A = P rows (m=t=l15-row), B = V^T frags
#pragma unroll
      for (int kc2 = 0; kc2 < 2; ++kc2) {
        vshort8 pf = *(const vshort8*)(&Paw[parow + (((4 * kc2 + quad) ^ swz) << 3)]);
#pragma unroll
        for (int dnt = 0; dnt < 4; ++dnt)
          oacc[st][dnt] = __builtin_amdgcn_mfma_f32_16x16x32_bf16(pf, vf[kc2][dnt], oacc[st][dnt], 0, 0, 0);
      }
    }
  };

  vshort8 kfA[4][2], kfB[4][2], vf[2][4];
  loadK(kfA, 0);
#pragma unroll 1
  for (int ss = 0; ss < 128; ss += 8) {   // 16 outer iters, 2 s-tiles each
    loadK(kfB, ss + 4);                   // prefetch next tile's K
    loadV(vf, ss);                        // V issued one phase ahead of use
    body(kfA, vf);
    loadK(kfA, (ss + 8) & 127);           // wraps harmlessly on last iter
    loadV(vf, ss + 4);
    body(kfB, vf);
  }

  // epilogue: l-reduce across quads, O/l + V residual (V from Vb blob)
#pragma unroll
  for (int st = 0; st < 4; ++st) {
    float l = lsum[st];
    l += __shfl_xor(l, 16, 64);
    l += __shfl_xor(l, 32, 64);
    const float inv = 1.0f / l;            // valid at lane index l15 (= t)
    float iT[4];
#pragma unroll
    for (int r = 0; r < 4; ++r) iT[r] = __shfl(inv, quad * 4 + r, 64);
    const int tstrip = tstrip0 + st;
#pragma unroll
    for (int nt = 0; nt < 4; ++nt) {
      uint2 vr = Vb[((hb + tstrip) * 4 + nt) * 64 + l15 * 4 + quad];
      float vres[4];
      vres[0] = bf2f((ushort)(vr.x & 0xFFFFu));
      vres[1] = bf2f((ushort)(vr.x >> 16));
      vres[2] = bf2f((ushort)(vr.y & 0xFFFFu));
      vres[3] = bf2f((ushort)(vr.y >> 16));
#pragma unroll
      for (int r = 0; r < 4; ++r) {
        const int t = tstrip * 16 + quad * 4 + r;
        out[((size_t)(b * T_SEQ + t)) * EMB + h * D_H + nt * 16 + l15] =
            oacc[st][nt][r] * iT[r] + vres[r];
      }
    }
  }
}

extern "C" void kernel_launch(void* const* d_in, const int* in_sizes, int n_in,
                              void* d_out, int out_size, void* d_ws, size_t ws_size,
                              hipStream_t stream) {
  const float* x  = (const float*)d_in[0];
  const float* Wq = (const float*)d_in[1];
  const float* Wk = (const float*)d_in[2];
  const float* Wv = (const float*)d_in[3];
  float* out = (float*)d_out;

  const size_t per = (size_t)64 * 128 * 4 * 16 * 4;  // 2,097,152 uint2 per blob
  uint2* Qb = (uint2*)d_ws;
  uint2* Kb = Qb + per;
  uint2* Vb = Kb + per;
  ushort* Wb = (ushort*)(Vb + per);  // 24 KB of bf16 W fragments
  // ws needed: 3 * per * 8 B + 24 KB = 50.4 MB

  wconv<<<1, 64, 0, stream>>>(Wq, Wk, Wv, Wb);
  proj_qkv<<<2048, 256, 0, stream>>>(x, Wb, Qb, Kb, Vb);
  attn_fused<<<512, 256, 0, stream>>>(Qb, Kb, Vb, out);
}

// Round 5
// 190.301 us; speedup vs baseline: 1.4272x; 1.4272x over previous
//
#include <hip/hip_runtime.h>

#define T_SEQ 2048
#define N_B   4
#define N_H   16
#define D_H   64
#define EMB   1024
#define CSC   0.18033688011f  // log2(e) / sqrt(64), folded into Q at projection

typedef __attribute__((ext_vector_type(8))) short vshort8;  // 8 bf16 (4 VGPRs)
typedef __attribute__((ext_vector_type(4))) float vfloat4;  // MFMA C/D

__device__ __forceinline__ ushort f2bf(float f) {
  union { float f; unsigned u; } v; v.f = f;
  unsigned u = v.u;
  return (ushort)((u + 0x7fffu + ((u >> 16) & 1u)) >> 16);  // RNE
}
__device__ __forceinline__ unsigned pk2bf(float a, float b) {  // [bf(a),bf(b)] in mem
  return (unsigned)f2bf(a) | ((unsigned)f2bf(b) << 16);
}
__device__ __forceinline__ float bf2f(ushort b) {
  union { unsigned u; float f; } v; v.u = ((unsigned)b) << 16;
  return v.f;
}
__device__ __forceinline__ float fexp2(float x) {
#if __has_builtin(__builtin_amdgcn_exp2f)
  return __builtin_amdgcn_exp2f(x);
#else
  return exp2f(x);
#endif
}
// pack hi16(lo),hi16(hi) -> [bf_trunc(lo), bf_trunc(hi)] in memory (1 v_perm)
__device__ __forceinline__ unsigned permhi(float hi, float lo) {
  union { float f; unsigned u; } a, b; a.f = hi; b.f = lo;
#if __has_builtin(__builtin_amdgcn_perm)
  return __builtin_amdgcn_perm(a.u, b.u, 0x07060302u);
#else
  return (a.u & 0xFFFF0000u) | (b.u >> 16);
#endif
}
__device__ __forceinline__ vshort8 cvt8(const float* p) {
  float4 w0 = *(const float4*)(p);
  float4 w1 = *(const float4*)(p + 4);
  vshort8 t;
  t[0] = (short)f2bf(w0.x); t[1] = (short)f2bf(w0.y);
  t[2] = (short)f2bf(w0.z); t[3] = (short)f2bf(w0.w);
  t[4] = (short)f2bf(w1.x); t[5] = (short)f2bf(w1.y);
  t[6] = (short)f2bf(w1.z); t[7] = (short)f2bf(w1.w);
  return t;
}

// Blob layout (per matrix): uint2 blob[bh][strip(128)][nt(4)][l15(16)][quad(4)]
//   Q/K: uint2 = 4 consecutive d at fixed row t/s (from swapped-MFMA C-layout)
//   V  : uint2 = 4 consecutive s at fixed d      (from normal-MFMA C-layout)

// ---------------- W pre-conversion (runs once, 1 wave) ----------------
__global__ void wconv(const float* __restrict__ Wq, const float* __restrict__ Wk,
                      const float* __restrict__ Wv, ushort* __restrict__ Wb) {
  const int lane = threadIdx.x & 63;
  const int l15  = lane & 15;
  const int quad = lane >> 4;
  const float* Ws[3] = {Wq, Wk, Wv};
#pragma unroll
  for (int m = 0; m < 3; ++m)
#pragma unroll
    for (int kc = 0; kc < 2; ++kc)
#pragma unroll
      for (int nt = 0; nt < 4; ++nt) {
        vshort8 t = cvt8(Ws[m] + (nt * 16 + l15) * D_H + kc * 32 + quad * 8);
        *(vshort8*)(&Wb[(((m * 2 + kc) * 4 + nt) * 64 + lane) * 8]) = t;
      }
}

// ---------------- QKV projection ----------------
// Wave = 16 rows (1 strip) of one head; W frags from pre-converted Wb (b128).
__global__ __launch_bounds__(256, 4) void proj_qkv(
    const float* __restrict__ x, const ushort* __restrict__ Wb,
    uint2* __restrict__ Qb, uint2* __restrict__ Kb, uint2* __restrict__ Vb) {
  const int wid  = threadIdx.x >> 6;
  const int lane = threadIdx.x & 63;
  const int l15  = lane & 15;
  const int quad = lane >> 4;
  const int gw    = blockIdx.x * 4 + wid;   // [0,8192)
  const int strip = gw >> 4;                // 16-row strip over B*T
  const int h     = gw & 15;
  const int r0    = strip * 16;
  const int b     = r0 >> 11;
  const int bh    = b * N_H + h;
  const int ts    = (r0 & (T_SEQ - 1)) >> 4;

  // x frag: lane holds x[r0+l15][h*64 + kc*32 + quad*8 + j]
  vshort8 afr[2];
  {
    const float* xp = x + (size_t)(r0 + l15) * EMB + h * D_H + quad * 8;
    afr[0] = cvt8(xp);
    afr[1] = cvt8(xp + 32);
  }

  uint2* Bs[3] = {Qb, Kb, Vb};
#pragma unroll
  for (int m = 0; m < 3; ++m) {
    vshort8 wf[2][4];
#pragma unroll
    for (int kc = 0; kc < 2; ++kc)
#pragma unroll
      for (int nt = 0; nt < 4; ++nt)
        wf[kc][nt] = *(const vshort8*)(&Wb[(((m * 2 + kc) * 4 + nt) * 64 + lane) * 8]);
    vfloat4 acc[4];
#pragma unroll
    for (int nt = 0; nt < 4; ++nt) acc[nt] = (vfloat4){0.f, 0.f, 0.f, 0.f};
#pragma unroll
    for (int kc = 0; kc < 2; ++kc)
#pragma unroll
      for (int nt = 0; nt < 4; ++nt)
        acc[nt] = (m < 2)
          ? __builtin_amdgcn_mfma_f32_16x16x32_bf16(wf[kc][nt], afr[kc], acc[nt], 0, 0, 0)
          : __builtin_amdgcn_mfma_f32_16x16x32_bf16(afr[kc], wf[kc][nt], acc[nt], 0, 0, 0);
    uint2* B = Bs[m];
#pragma unroll
    for (int nt = 0; nt < 4; ++nt) {
      vfloat4 a = acc[nt];
      if (m == 0) { a[0] *= CSC; a[1] *= CSC; a[2] *= CSC; a[3] *= CSC; }
      uint2 w;
      w.x = pk2bf(a[0], a[1]);
      w.y = pk2bf(a[2], a[3]);
      B[(((size_t)bh * 128 + ts) * 4 + nt) * 64 + l15 * 4 + quad] = w;
    }
  }
}

// ---------------- fused flash attention (no-max softmax) + V residual --------
// Wave = 32 q-rows (2 strips), block = 4 waves (128 t) of one (b,h).
// Single-buffered fragment loads (R3 structure); occupancy 3 waves/SIMD.
__global__ __launch_bounds__(256, 3) void attn_fused(
    const uint2* __restrict__ Qb, const uint2* __restrict__ Kb,
    const uint2* __restrict__ Vb, float* __restrict__ out) {
  __shared__ ushort Pa[4 * 1024];  // per-wave 16x64 P tile, XOR-swizzled chunks

  const int tid  = threadIdx.x;
  const int wid  = tid >> 6;
  const int lane = tid & 63;
  const int l15  = lane & 15;
  const int quad = lane >> 4;
  const int qh   = quad >> 1;
  const int q1   = quad & 1;

  // XCD swizzle: consecutive per-XCD slots share a bh -> K/V stay in that L2
  const int blk  = blockIdx.x;                 // [0,1024)
  const int work = (blk & 7) * 128 + (blk >> 3);
  const int bh   = work >> 4;
  const int tblk = work & 15;
  const int b = bh >> 4, h = bh & 15;
  const int tstrip0 = tblk * 8 + wid * 2;      // first of this wave's 2 strips

  const size_t hb = (size_t)bh * 128;
  const int laneoff = l15 * 4 + 2 * q1;        // uint2 units

  // Q frags (B-operand of S^T): lane holds Q[t=l15][d=kc*32+quad*8+j] * CSC
  vshort8 qf[2][2];
#pragma unroll
  for (int st = 0; st < 2; ++st)
#pragma unroll
    for (int kc = 0; kc < 2; ++kc)
      qf[st][kc] = *(const vshort8*)(&Qb[((hb + tstrip0 + st) * 4 + 2 * kc + qh) * 64 + laneoff]);

  vfloat4 oacc[2][4];
  float lsum[2];
#pragma unroll
  for (int st = 0; st < 2; ++st) {
#pragma unroll
    for (int nt = 0; nt < 4; ++nt) oacc[st][nt] = (vfloat4){0.f, 0.f, 0.f, 0.f};
    lsum[st] = 0.f;
  }

  ushort* Paw = &Pa[wid * 1024];
  const int parow = l15 * 64;   // elements
  const int swz   = l15 & 7;

  for (int ss = 0; ss < 128; ss += 4) {  // 32 s-tiles of 64
    // K A-frags: lane holds K[s=16snt+l15][d=kc*32+quad*8+j]
    vshort8 kf[4][2];
#pragma unroll
    for (int snt = 0; snt < 4; ++snt)
#pragma unroll
      for (int kc = 0; kc < 2; ++kc)
        kf[snt][kc] = *(const vshort8*)(&Kb[((hb + ss + snt) * 4 + 2 * kc + qh) * 64 + laneoff]);
    // V^T B-frags: lane holds V[s=kc2*32+quad*8+j][d=16dnt+l15]
    vshort8 vf[2][4];
#pragma unroll
    for (int kc2 = 0; kc2 < 2; ++kc2)
#pragma unroll
      for (int dnt = 0; dnt < 4; ++dnt)
        vf[kc2][dnt] = *(const vshort8*)(&Vb[((hb + ss + 2 * kc2 + qh) * 4 + dnt) * 64 + laneoff]);

#pragma unroll
    for (int st = 0; st < 2; ++st) {
      // S^T = K * Q^T : C holds (s = 16nt+4quad+r, t = l15)
      vfloat4 sacc[4];
#pragma unroll
      for (int nt = 0; nt < 4; ++nt) sacc[nt] = (vfloat4){0.f, 0.f, 0.f, 0.f};
#pragma unroll
      for (int kc = 0; kc < 2; ++kc)
#pragma unroll
        for (int nt = 0; nt < 4; ++nt)
          sacc[nt] = __builtin_amdgcn_mfma_f32_16x16x32_bf16(kf[nt][kc], qf[st][kc], sacc[nt], 0, 0, 0);

      // no-max softmax: p = exp2(sacc); per-lane partial l; P -> Pa (swizzled)
      float ls = 0.f;
#pragma unroll
      for (int nt = 0; nt < 4; ++nt) {
        const float p0 = fexp2(sacc[nt][0]);
        const float p1 = fexp2(sacc[nt][1]);
        const float p2 = fexp2(sacc[nt][2]);
        const float p3 = fexp2(sacc[nt][3]);
        ls += (p0 + p1) + (p2 + p3);
        uint2 w;
        w.x = permhi(p1, p0);
        w.y = permhi(p3, p2);
        *(uint2*)(&Paw[parow + (((2 * nt + qh) ^ swz) << 3) + 4 * q1]) = w;
      }
      lsum[st] += ls;

      // O += P * V : A = P rows (m=t=l15-row), B = V^T frags
#pragma unroll
      for (int kc2 = 0; kc2 < 2; ++kc2) {
        vshort8 pf = *(const vshort8*)(&Paw[parow + (((4 * kc2 + quad) ^ swz) << 3)]);
#pragma unroll
        for (int dnt = 0; dnt < 4; ++dnt)
          oacc[st][dnt] = __builtin_amdgcn_mfma_f32_16x16x32_bf16(pf, vf[kc2][dnt], oacc[st][dnt], 0, 0, 0);
      }
    }
  }

  // epilogue: l-reduce across quads, O/l + V residual (V from Vb blob)
#pragma unroll
  for (int st = 0; st < 2; ++st) {
    float l = lsum[st];
    l += __shfl_xor(l, 16, 64);
    l += __shfl_xor(l, 32, 64);
    const float inv = 1.0f / l;            // valid at lane index l15 (= t)
    float iT[4];
#pragma unroll
    for (int r = 0; r < 4; ++r) iT[r] = __shfl(inv, quad * 4 + r, 64);
    const int tstrip = tstrip0 + st;
#pragma unroll
    for (int nt = 0; nt < 4; ++nt) {
      uint2 vr = Vb[((hb + tstrip) * 4 + nt) * 64 + l15 * 4 + quad];
      float vres[4];
      vres[0] = bf2f((ushort)(vr.x & 0xFFFFu));
      vres[1] = bf2f((ushort)(vr.x >> 16));
      vres[2] = bf2f((ushort)(vr.y & 0xFFFFu));
      vres[3] = bf2f((ushort)(vr.y >> 16));
#pragma unroll
      for (int r = 0; r < 4; ++r) {
        const int t = tstrip * 16 + quad * 4 + r;
        out[((size_t)(b * T_SEQ + t)) * EMB + h * D_H + nt * 16 + l15] =
            oacc[st][nt][r] * iT[r] + vres[r];
      }
    }
  }
}

extern "C" void kernel_launch(void* const* d_in, const int* in_sizes, int n_in,
                              void* d_out, int out_size, void* d_ws, size_t ws_size,
                              hipStream_t stream) {
  const float* x  = (const float*)d_in[0];
  const float* Wq = (const float*)d_in[1];
  const float* Wk = (const float*)d_in[2];
  const float* Wv = (const float*)d_in[3];
  float* out = (float*)d_out;

  const size_t per = (size_t)64 * 128 * 4 * 16 * 4;  // 2,097,152 uint2 per blob
  uint2* Qb = (uint2*)d_ws;
  uint2* Kb = Qb + per;
  uint2* Vb = Kb + per;
  ushort* Wb = (ushort*)(Vb + per);  // 24 KB of bf16 W fragments
  // ws needed: 3 * per * 8 B + 24 KB = 50.4 MB

  wconv<<<1, 64, 0, stream>>>(Wq, Wk, Wv, Wb);
  proj_qkv<<<2048, 256, 0, stream>>>(x, Wb, Qb, Kb, Vb);
  attn_fused<<<1024, 256, 0, stream>>>(Qb, Kb, Vb, out);
}

// Round 6
// 173.205 us; speedup vs baseline: 1.5681x; 1.0987x over previous
//
#include <hip/hip_runtime.h>

#define T_SEQ 2048
#define N_B   4
#define N_H   16
#define D_H   64
#define EMB   1024
#define CSC   0.18033688011f  // log2(e) / sqrt(64), folded into Q at projection

typedef __attribute__((ext_vector_type(8))) short vshort8;  // 8 bf16 (4 VGPRs)
typedef __attribute__((ext_vector_type(4))) float vfloat4;  // MFMA C/D

__device__ __forceinline__ ushort f2bf(float f) {
  union { float f; unsigned u; } v; v.f = f;
  unsigned u = v.u;
  return (ushort)((u + 0x7fffu + ((u >> 16) & 1u)) >> 16);  // RNE
}
__device__ __forceinline__ unsigned pk2bf(float a, float b) {  // [bf(a),bf(b)] in mem
  return (unsigned)f2bf(a) | ((unsigned)f2bf(b) << 16);
}
__device__ __forceinline__ float bf2f(ushort b) {
  union { unsigned u; float f; } v; v.u = ((unsigned)b) << 16;
  return v.f;
}
__device__ __forceinline__ float fexp2(float x) {
#if __has_builtin(__builtin_amdgcn_exp2f)
  return __builtin_amdgcn_exp2f(x);
#else
  return exp2f(x);
#endif
}
// pack hi16(lo),hi16(hi) -> [bf_trunc(lo), bf_trunc(hi)] in memory (1 v_perm)
__device__ __forceinline__ unsigned permhi(float hi, float lo) {
  union { float f; unsigned u; } a, b; a.f = hi; b.f = lo;
#if __has_builtin(__builtin_amdgcn_perm)
  return __builtin_amdgcn_perm(a.u, b.u, 0x07060302u);
#else
  return (a.u & 0xFFFF0000u) | (b.u >> 16);
#endif
}
__device__ __forceinline__ vshort8 cvt8(const float* p) {
  float4 w0 = *(const float4*)(p);
  float4 w1 = *(const float4*)(p + 4);
  vshort8 t;
  t[0] = (short)f2bf(w0.x); t[1] = (short)f2bf(w0.y);
  t[2] = (short)f2bf(w0.z); t[3] = (short)f2bf(w0.w);
  t[4] = (short)f2bf(w1.x); t[5] = (short)f2bf(w1.y);
  t[6] = (short)f2bf(w1.z); t[7] = (short)f2bf(w1.w);
  return t;
}
// async global -> LDS, 16 B per lane; lds dest = wave-uniform base + lane*16
__device__ __forceinline__ void gload_lds16(const void* g, void* l) {
  __builtin_amdgcn_global_load_lds((const __attribute__((address_space(1))) void*)g,
                                   (__attribute__((address_space(3))) void*)l, 16, 0, 0);
}

// Blob layout (per matrix): uint2 blob[bh][strip(128)][nt(4)][l15(16)][quad(4)]
//   Q/K: uint2 = 4 consecutive d at fixed row t/s (from swapped-MFMA C-layout)
//   V  : uint2 = 4 consecutive s at fixed d      (from normal-MFMA C-layout)
// A 64-row tile (4 strips) is 8 KB flat-contiguous -> straight LDS staging.

// ---------------- W pre-conversion (runs once, 1 wave) ----------------
__global__ void wconv(const float* __restrict__ Wq, const float* __restrict__ Wk,
                      const float* __restrict__ Wv, ushort* __restrict__ Wb) {
  const int lane = threadIdx.x & 63;
  const int l15  = lane & 15;
  const int quad = lane >> 4;
  const float* Ws[3] = {Wq, Wk, Wv};
#pragma unroll
  for (int m = 0; m < 3; ++m)
#pragma unroll
    for (int kc = 0; kc < 2; ++kc)
#pragma unroll
      for (int nt = 0; nt < 4; ++nt) {
        vshort8 t = cvt8(Ws[m] + (nt * 16 + l15) * D_H + kc * 32 + quad * 8);
        *(vshort8*)(&Wb[(((m * 2 + kc) * 4 + nt) * 64 + lane) * 8]) = t;
      }
}

// ---------------- QKV projection ----------------
// Wave = 16 rows (1 strip) of one head; W frags from pre-converted Wb (b128).
__global__ __launch_bounds__(256, 4) void proj_qkv(
    const float* __restrict__ x, const ushort* __restrict__ Wb,
    uint2* __restrict__ Qb, uint2* __restrict__ Kb, uint2* __restrict__ Vb) {
  const int wid  = threadIdx.x >> 6;
  const int lane = threadIdx.x & 63;
  const int l15  = lane & 15;
  const int quad = lane >> 4;
  const int gw    = blockIdx.x * 4 + wid;   // [0,8192)
  const int strip = gw >> 4;                // 16-row strip over B*T
  const int h     = gw & 15;
  const int r0    = strip * 16;
  const int b     = r0 >> 11;
  const int bh    = b * N_H + h;
  const int ts    = (r0 & (T_SEQ - 1)) >> 4;

  // x frag: lane holds x[r0+l15][h*64 + kc*32 + quad*8 + j]
  vshort8 afr[2];
  {
    const float* xp = x + (size_t)(r0 + l15) * EMB + h * D_H + quad * 8;
    afr[0] = cvt8(xp);
    afr[1] = cvt8(xp + 32);
  }

  uint2* Bs[3] = {Qb, Kb, Vb};
#pragma unroll
  for (int m = 0; m < 3; ++m) {
    vshort8 wf[2][4];
#pragma unroll
    for (int kc = 0; kc < 2; ++kc)
#pragma unroll
      for (int nt = 0; nt < 4; ++nt)
        wf[kc][nt] = *(const vshort8*)(&Wb[(((m * 2 + kc) * 4 + nt) * 64 + lane) * 8]);
    vfloat4 acc[4];
#pragma unroll
    for (int nt = 0; nt < 4; ++nt) acc[nt] = (vfloat4){0.f, 0.f, 0.f, 0.f};
#pragma unroll
    for (int kc = 0; kc < 2; ++kc)
#pragma unroll
      for (int nt = 0; nt < 4; ++nt)
        acc[nt] = (m < 2)
          ? __builtin_amdgcn_mfma_f32_16x16x32_bf16(wf[kc][nt], afr[kc], acc[nt], 0, 0, 0)
          : __builtin_amdgcn_mfma_f32_16x16x32_bf16(afr[kc], wf[kc][nt], acc[nt], 0, 0, 0);
    uint2* B = Bs[m];
#pragma unroll
    for (int nt = 0; nt < 4; ++nt) {
      vfloat4 a = acc[nt];
      if (m == 0) { a[0] *= CSC; a[1] *= CSC; a[2] *= CSC; a[3] *= CSC; }
      uint2 w;
      w.x = pk2bf(a[0], a[1]);
      w.y = pk2bf(a[2], a[3]);
      B[(((size_t)bh * 128 + ts) * 4 + nt) * 64 + l15 * 4 + quad] = w;
    }
  }
}

// ---------------- fused flash attention (no-max softmax) + V residual --------
// Wave = 64 q-rows (4 strips), block = 4 waves (256 t) of one (b,h).
// K/V tiles staged once per block into double-buffered LDS via
// global_load_lds (width 16); prefetch of tile i+1 overlaps compute of tile i.
__global__ __launch_bounds__(256, 2) void attn_fused(
    const uint2* __restrict__ Qb, const uint2* __restrict__ Kb,
    const uint2* __restrict__ Vb, float* __restrict__ out) {
  __shared__ __align__(16) ushort Ksh[2][4096];  // 8 KB per buffer (64 s x 64 d)
  __shared__ __align__(16) ushort Vsh[2][4096];
  __shared__ __align__(16) ushort Pa[4 * 1024];  // per-wave 16x64 P, XOR-swizzled

  const int tid  = threadIdx.x;
  const int wid  = tid >> 6;
  const int lane = tid & 63;
  const int l15  = lane & 15;
  const int quad = lane >> 4;
  const int qh   = quad >> 1;
  const int q1   = quad & 1;

  // XCD swizzle: 16 consecutive per-XCD slots share a bh -> K/V stay in that L2
  const int blk  = blockIdx.x;                 // [0,512)
  const int work = (blk & 7) * 64 + (blk >> 3);
  const int bh   = work >> 3;
  const int tblk = work & 7;
  const int b = bh >> 4, h = bh & 15;
  const int tstrip0 = tblk * 16 + wid * 4;     // first of this wave's 4 strips

  const size_t hb = (size_t)bh * 128;
  const int laneoff = l15 * 4 + 2 * q1;        // uint2 units

  // staging offsets: this thread copies 2x16B of K and V per tile
  const int soff = wid * 2048 + lane * 16;     // bytes within the 8 KB tile

  // Q frags (B-operand of S^T): lane holds Q[t=l15][d=kc*32+quad*8+j] * CSC
  vshort8 qf[4][2];
#pragma unroll
  for (int st = 0; st < 4; ++st)
#pragma unroll
    for (int kc = 0; kc < 2; ++kc)
      qf[st][kc] = *(const vshort8*)(&Qb[((hb + tstrip0 + st) * 4 + 2 * kc + qh) * 64 + laneoff]);

  vfloat4 oacc[4][4];
  float lsum[4];
#pragma unroll
  for (int st = 0; st < 4; ++st) {
#pragma unroll
    for (int nt = 0; nt < 4; ++nt) oacc[st][nt] = (vfloat4){0.f, 0.f, 0.f, 0.f};
    lsum[st] = 0.f;
  }

  ushort* Paw = &Pa[wid * 1024];
  const int parow = l15 * 64;   // elements
  const int swz   = l15 & 7;

  auto stage = [&](int buf, int ss) {
    const char* kg = (const char*)(Kb + (hb + ss) * 256);
    const char* vg = (const char*)(Vb + (hb + ss) * 256);
    char* kl = (char*)&Ksh[buf][0];
    char* vl = (char*)&Vsh[buf][0];
#pragma unroll
    for (int r = 0; r < 2; ++r) {
      gload_lds16(kg + soff + r * 1024, kl + soff + r * 1024);
      gload_lds16(vg + soff + r * 1024, vl + soff + r * 1024);
    }
  };

  stage(0, 0);

  for (int ss = 0; ss < 128; ss += 4) {  // 32 s-tiles of 64
    const int buf = (ss >> 2) & 1;
    __syncthreads();                     // publishes stage(buf); drains vmcnt
    if (ss + 4 < 128) stage(buf ^ 1, ss + 4);

    const uint2* Kc = (const uint2*)&Ksh[buf][0];
    const uint2* Vc = (const uint2*)&Vsh[buf][0];

    // K A-frags: lane holds K[s=16snt+l15][d=kc*32+quad*8+j]
    vshort8 kf[4][2];
#pragma unroll
    for (int snt = 0; snt < 4; ++snt)
#pragma unroll
      for (int kc = 0; kc < 2; ++kc)
        kf[snt][kc] = *(const vshort8*)(Kc + (snt * 4 + 2 * kc + qh) * 64 + laneoff);
    // V^T B-frags: lane holds V[s=kc2*32+quad*8+j][d=16dnt+l15]
    vshort8 vf[2][4];
#pragma unroll
    for (int kc2 = 0; kc2 < 2; ++kc2)
#pragma unroll
      for (int dnt = 0; dnt < 4; ++dnt)
        vf[kc2][dnt] = *(const vshort8*)(Vc + ((2 * kc2 + qh) * 4 + dnt) * 64 + laneoff);

#pragma unroll
    for (int st = 0; st < 4; ++st) {
      // S^T = K * Q^T : C holds (s = 16nt+4quad+r, t = l15)
      vfloat4 sacc[4];
#pragma unroll
      for (int nt = 0; nt < 4; ++nt) sacc[nt] = (vfloat4){0.f, 0.f, 0.f, 0.f};
#pragma unroll
      for (int kc = 0; kc < 2; ++kc)
#pragma unroll
        for (int nt = 0; nt < 4; ++nt)
          sacc[nt] = __builtin_amdgcn_mfma_f32_16x16x32_bf16(kf[nt][kc], qf[st][kc], sacc[nt], 0, 0, 0);

      // no-max softmax: p = exp2(sacc); per-lane partial l; P -> Pa (swizzled)
      float ls = 0.f;
#pragma unroll
      for (int nt = 0; nt < 4; ++nt) {
        const float p0 = fexp2(sacc[nt][0]);
        const float p1 = fexp2(sacc[nt][1]);
        const float p2 = fexp2(sacc[nt][2]);
        const float p3 = fexp2(sacc[nt][3]);
        ls += (p0 + p1) + (p2 + p3);
        uint2 w;
        w.x = permhi(p1, p0);
        w.y = permhi(p3, p2);
        *(uint2*)(&Paw[parow + (((2 * nt + qh) ^ swz) << 3) + 4 * q1]) = w;
      }
      lsum[st] += ls;

      // O += P * V : A = P rows (m=t=l15-row), B = V^T frags
#pragma unroll
      for (int kc2 = 0; kc2 < 2; ++kc2) {
        vshort8 pf = *(const vshort8*)(&Paw[parow + (((4 * kc2 + quad) ^ swz) << 3)]);
#pragma unroll
        for (int dnt = 0; dnt < 4; ++dnt)
          oacc[st][dnt] = __builtin_amdgcn_mfma_f32_16x16x32_bf16(pf, vf[kc2][dnt], oacc[st][dnt], 0, 0, 0);
      }
    }
  }

  // epilogue: l-reduce across quads, O/l + V residual (V from Vb blob)
#pragma unroll
  for (int st = 0; st < 4; ++st) {
    float l = lsum[st];
    l += __shfl_xor(l, 16, 64);
    l += __shfl_xor(l, 32, 64);
    const float inv = 1.0f / l;            // valid at lane index l15 (= t)
    float iT[4];
#pragma unroll
    for (int r = 0; r < 4; ++r) iT[r] = __shfl(inv, quad * 4 + r, 64);
    const int tstrip = tstrip0 + st;
#pragma unroll
    for (int nt = 0; nt < 4; ++nt) {
      uint2 vr = Vb[((hb + tstrip) * 4 + nt) * 64 + l15 * 4 + quad];
      float vres[4];
      vres[0] = bf2f((ushort)(vr.x & 0xFFFFu));
      vres[1] = bf2f((ushort)(vr.x >> 16));
      vres[2] = bf2f((ushort)(vr.y & 0xFFFFu));
      vres[3] = bf2f((ushort)(vr.y >> 16));
#pragma unroll
      for (int r = 0; r < 4; ++r) {
        const int t = tstrip * 16 + quad * 4 + r;
        out[((size_t)(b * T_SEQ + t)) * EMB + h * D_H + nt * 16 + l15] =
            oacc[st][nt][r] * iT[r] + vres[r];
      }
    }
  }
}

extern "C" void kernel_launch(void* const* d_in, const int* in_sizes, int n_in,
                              void* d_out, int out_size, void* d_ws, size_t ws_size,
                              hipStream_t stream) {
  const float* x  = (const float*)d_in[0];
  const float* Wq = (const float*)d_in[1];
  const float* Wk = (const float*)d_in[2];
  const float* Wv = (const float*)d_in[3];
  float* out = (float*)d_out;

  const size_t per = (size_t)64 * 128 * 4 * 16 * 4;  // 2,097,152 uint2 per blob
  uint2* Qb = (uint2*)d_ws;
  uint2* Kb = Qb + per;
  uint2* Vb = Kb + per;
  ushort* Wb = (ushort*)(Vb + per);  // 24 KB of bf16 W fragments
  // ws needed: 3 * per * 8 B + 24 KB = 50.4 MB

  wconv<<<1, 64, 0, stream>>>(Wq, Wk, Wv, Wb);
  proj_qkv<<<2048, 256, 0, stream>>>(x, Wb, Qb, Kb, Vb);
  attn_fused<<<512, 256, 0, stream>>>(Qb, Kb, Vb, out);
}

// Round 7
// 172.893 us; speedup vs baseline: 1.5710x; 1.0018x over previous
//
#include <hip/hip_runtime.h>

#define T_SEQ 2048
#define N_B   4
#define N_H   16
#define D_H   64
#define EMB   1024
#define CSC   0.18033688011f  // log2(e) / sqrt(64), folded into Q at projection

typedef __attribute__((ext_vector_type(8))) short   vshort8;   // 8 bf16 (4 VGPRs)
typedef __attribute__((ext_vector_type(4))) float   vfloat4;   // 16x16 C/D
typedef __attribute__((ext_vector_type(16))) float  vfloat16;  // 32x32 C/D

__device__ __forceinline__ ushort f2bf(float f) {
  union { float f; unsigned u; } v; v.f = f;
  unsigned u = v.u;
  return (ushort)((u + 0x7fffu + ((u >> 16) & 1u)) >> 16);  // RNE
}
__device__ __forceinline__ unsigned pk2bf(float a, float b) {  // [bf(a),bf(b)] in mem
  return (unsigned)f2bf(a) | ((unsigned)f2bf(b) << 16);
}
__device__ __forceinline__ float bf2f(ushort b) {
  union { unsigned u; float f; } v; v.u = ((unsigned)b) << 16;
  return v.f;
}
__device__ __forceinline__ float fexp2(float x) {
#if __has_builtin(__builtin_amdgcn_exp2f)
  return __builtin_amdgcn_exp2f(x);
#else
  return exp2f(x);
#endif
}
// pack hi16(lo),hi16(hi) -> [bf_trunc(lo), bf_trunc(hi)] in memory (1 v_perm)
__device__ __forceinline__ unsigned permhi(float hi, float lo) {
  union { float f; unsigned u; } a, b; a.f = hi; b.f = lo;
#if __has_builtin(__builtin_amdgcn_perm)
  return __builtin_amdgcn_perm(a.u, b.u, 0x07060302u);
#else
  return (a.u & 0xFFFF0000u) | (b.u >> 16);
#endif
}
__device__ __forceinline__ vshort8 cvt8(const float* p) {
  float4 w0 = *(const float4*)(p);
  float4 w1 = *(const float4*)(p + 4);
  vshort8 t;
  t[0] = (short)f2bf(w0.x); t[1] = (short)f2bf(w0.y);
  t[2] = (short)f2bf(w0.z); t[3] = (short)f2bf(w0.w);
  t[4] = (short)f2bf(w1.x); t[5] = (short)f2bf(w1.y);
  t[6] = (short)f2bf(w1.z); t[7] = (short)f2bf(w1.w);
  return t;
}

// ---- 32-lane-fragment blob layouts (uint4 = 8 bf16 = one lane-frag) ----
// Q/K: uint4 idx = ((bh*64 + t32)*4 + dstep)*64 + l31*2 + h
//      lane (l31,h) frag = X[t = 32*t32 + l31][d = 16*dstep + 8*h + 0..7]
// V  : uint4 idx = (((bh*32 + s64)*4 + step)*2 + dblk)*64 + l31*2 + h
//      lane (l31,h) frag = V[s = 64*s64 + 16*step + 8*h + 0..7][d = 32*dblk + l31]

// ---------------- W pre-conversion (runs once, 1 wave) ----------------
__global__ void wconv(const float* __restrict__ Wq, const float* __restrict__ Wk,
                      const float* __restrict__ Wv, ushort* __restrict__ Wb) {
  const int lane = threadIdx.x & 63;
  const int l15  = lane & 15;
  const int quad = lane >> 4;
  const float* Ws[3] = {Wq, Wk, Wv};
#pragma unroll
  for (int m = 0; m < 3; ++m)
#pragma unroll
    for (int kc = 0; kc < 2; ++kc)
#pragma unroll
      for (int nt = 0; nt < 4; ++nt) {
        vshort8 t = cvt8(Ws[m] + (nt * 16 + l15) * D_H + kc * 32 + quad * 8);
        *(vshort8*)(&Wb[(((m * 2 + kc) * 4 + nt) * 64 + lane) * 8]) = t;
      }
}

// ---------------- QKV projection (16x16 MFMA compute, 32-frag stores) -------
__global__ __launch_bounds__(256, 4) void proj_qkv(
    const float* __restrict__ x, const ushort* __restrict__ Wb,
    uint2* __restrict__ Qb, uint2* __restrict__ Kb, uint2* __restrict__ Vb) {
  const int wid  = threadIdx.x >> 6;
  const int lane = threadIdx.x & 63;
  const int l15  = lane & 15;
  const int q    = lane >> 4;
  const int gw    = blockIdx.x * 4 + wid;   // [0,8192)
  const int strip = gw >> 4;                // 16-row strip over B*T
  const int hd    = gw & 15;
  const int r0    = strip * 16;
  const int b     = r0 >> 11;
  const int bh    = b * N_H + hd;
  const int ts    = (r0 & (T_SEQ - 1)) >> 4;  // strip index within head [0,128)

  // x frag: lane holds x[r0+l15][hd*64 + kc*32 + q*8 + j]
  vshort8 afr[2];
  {
    const float* xp = x + (size_t)(r0 + l15) * EMB + hd * D_H + q * 8;
    afr[0] = cvt8(xp);
    afr[1] = cvt8(xp + 32);
  }

  uint2* Bs[3] = {Qb, Kb, Vb};
#pragma unroll
  for (int m = 0; m < 3; ++m) {
    vshort8 wf[2][4];
#pragma unroll
    for (int kc = 0; kc < 2; ++kc)
#pragma unroll
      for (int nt = 0; nt < 4; ++nt)
        wf[kc][nt] = *(const vshort8*)(&Wb[(((m * 2 + kc) * 4 + nt) * 64 + lane) * 8]);
    vfloat4 acc[4];
#pragma unroll
    for (int nt = 0; nt < 4; ++nt) acc[nt] = (vfloat4){0.f, 0.f, 0.f, 0.f};
#pragma unroll
    for (int kc = 0; kc < 2; ++kc)
#pragma unroll
      for (int nt = 0; nt < 4; ++nt)
        acc[nt] = (m < 2)
          ? __builtin_amdgcn_mfma_f32_16x16x32_bf16(wf[kc][nt], afr[kc], acc[nt], 0, 0, 0)
          : __builtin_amdgcn_mfma_f32_16x16x32_bf16(afr[kc], wf[kc][nt], acc[nt], 0, 0, 0);
    uint2* B = Bs[m];
#pragma unroll
    for (int nt = 0; nt < 4; ++nt) {
      vfloat4 a = acc[nt];
      if (m == 0) { a[0] *= CSC; a[1] *= CSC; a[2] *= CSC; a[3] *= CSC; }
      uint2 w;
      w.x = pk2bf(a[0], a[1]);
      w.y = pk2bf(a[2], a[3]);
      size_t idx;
      if (m < 2) {
        // swapped C: lane holds (d = 16nt+4q+r, t = l15); t32 = ts>>1
        idx = ((size_t)(bh * 64 + (ts >> 1)) * 4 + nt) * 128
              + (l15 + 16 * (ts & 1)) * 4 + q;
      } else {
        // normal C: lane holds (s = 16(ts&3)+4q+r local in s64, d = 16nt+l15)
        idx = (((size_t)(bh * 32 + (ts >> 2)) * 4 + (ts & 3)) * 2 + (nt >> 1)) * 128
              + 64 * (nt & 1) + l15 * 4 + q;
      }
      B[idx] = w;
    }
  }
}

// ---------------- fused flash attention (no-max softmax) + V residual -------
// Wave = 64 q-rows (2 t32-blocks), block = 4 waves (256 t) of one (b,h).
// 32x32x16 MFMA; P transposed C->A in-register via one shfl_xor(32) exchange.
// Zero LDS, zero barriers.
__global__ __launch_bounds__(256, 2) void attn_fused(
    const uint4* __restrict__ Qb, const uint4* __restrict__ Kb,
    const uint4* __restrict__ Vb, float* __restrict__ out) {
  const int tid  = threadIdx.x;
  const int wid  = tid >> 6;
  const int lane = tid & 63;
  const int l31  = lane & 31;
  const int h    = lane >> 5;

  // XCD swizzle: 16 consecutive per-XCD slots share a bh -> K/V stay in that L2
  const int blk  = blockIdx.x;                 // [0,512)
  const int work = (blk & 7) * 64 + (blk >> 3);
  const int bh   = work >> 3;
  const int tblk8 = work & 7;
  const int b = bh >> 4, hh = bh & 15;
  const int T64 = tblk8 * 4 + wid;             // this wave's 64-t chunk [0,32)

  const int lo = l31 * 2 + h;                  // lane offset in uint4 units

  // Q B-frags: lane holds Q[t = 32*t32 + l31][d = 16ds + 8h + j] * CSC
  vshort8 qf[2][4];
#pragma unroll
  for (int tb = 0; tb < 2; ++tb)
#pragma unroll
    for (int ds = 0; ds < 4; ++ds)
      qf[tb][ds] = *(const vshort8*)&Qb[((size_t)(bh * 64 + 2 * T64 + tb) * 4 + ds) * 64 + lo];

  vfloat16 oacc[2][2];
#pragma unroll
  for (int tb = 0; tb < 2; ++tb)
#pragma unroll
    for (int db = 0; db < 2; ++db)
#pragma unroll
      for (int i = 0; i < 16; ++i) oacc[tb][db][i] = 0.f;
  float lsum[2] = {0.f, 0.f};

#pragma unroll 1
  for (int ss = 0; ss < 32; ++ss) {  // 32 s-tiles of 64
    // K A-frags: lane holds K[s = 64ss + 32sb + l31][d = 16ds + 8h + j]
    vshort8 kf[2][4];
#pragma unroll
    for (int sb = 0; sb < 2; ++sb)
#pragma unroll
      for (int ds = 0; ds < 4; ++ds)
        kf[sb][ds] = *(const vshort8*)&Kb[((size_t)(bh * 64 + 2 * ss + sb) * 4 + ds) * 64 + lo];
    // V B-frags: lane holds V[s = 64ss + 16st + 8h + j][d = 32db + l31]
    vshort8 vf[4][2];
#pragma unroll
    for (int st = 0; st < 4; ++st)
#pragma unroll
      for (int db = 0; db < 2; ++db)
        vf[st][db] = *(const vshort8*)&Vb[(((size_t)(bh * 32 + ss) * 4 + st) * 2 + db) * 64 + lo];

#pragma unroll
    for (int tb = 0; tb < 2; ++tb) {
      // S^T = K*Q^T : C holds (s-local = (r&3)+8(r>>2)+4h + 32sb, t = l31)
      vfloat16 sacc[2];
#pragma unroll
      for (int sb = 0; sb < 2; ++sb) {
#pragma unroll
        for (int i = 0; i < 16; ++i) sacc[sb][i] = 0.f;
#pragma unroll
        for (int ds = 0; ds < 4; ++ds)
          sacc[sb] = __builtin_amdgcn_mfma_f32_32x32x16_bf16(kf[sb][ds], qf[tb][ds], sacc[sb], 0, 0, 0);
      }
      // no-max softmax + in-register C->A transpose of P
      float p[2][16];
      float ls = 0.f;
#pragma unroll
      for (int sb = 0; sb < 2; ++sb)
#pragma unroll
        for (int r = 0; r < 16; ++r) {
          p[sb][r] = fexp2(sacc[sb][r]);
          ls += p[sb][r];
        }
      lsum[tb] += ls;

#pragma unroll
      for (int sb = 0; sb < 2; ++sb)
#pragma unroll
        for (int g = 0; g < 2; ++g) {
          // own packs: OL = s 16g+4h+{0..3}, OH = s 16g+8+4h+{0..3} (local in sb)
          const unsigned OL0 = permhi(p[sb][8 * g + 1], p[sb][8 * g + 0]);
          const unsigned OL1 = permhi(p[sb][8 * g + 3], p[sb][8 * g + 2]);
          const unsigned OH0 = permhi(p[sb][8 * g + 5], p[sb][8 * g + 4]);
          const unsigned OH1 = permhi(p[sb][8 * g + 7], p[sb][8 * g + 6]);
          // exchange: h=0 needs partner's OL, h=1 needs partner's OH
          const unsigned s0 = h ? OL0 : OH0;
          const unsigned s1 = h ? OL1 : OH1;
          const unsigned r0 = (unsigned)__shfl_xor((int)s0, 32, 64);
          const unsigned r1 = (unsigned)__shfl_xor((int)s1, 32, 64);
          union { unsigned u[4]; vshort8 v; } pa;
          pa.u[0] = h ? r0 : OL0;
          pa.u[1] = h ? r1 : OL1;
          pa.u[2] = h ? OH0 : r0;
          pa.u[3] = h ? OH1 : r1;
          const int st = 2 * sb + g;
#pragma unroll
          for (int db = 0; db < 2; ++db)
            oacc[tb][db] = __builtin_amdgcn_mfma_f32_32x32x16_bf16(pa.v, vf[st][db], oacc[tb][db], 0, 0, 0);
        }
    }
  }

  // ---- epilogue: l-reduce, O/l + V residual ----
  const uint2* Vb2 = (const uint2*)Vb;
#pragma unroll
  for (int tb = 0; tb < 2; ++tb) {
    const float l = lsum[tb] + __shfl_xor(lsum[tb], 32, 64);
    const float inv = 1.0f / l;                // valid at t-local = l31
    const int T32 = 2 * T64 + tb;
#pragma unroll
    for (int db = 0; db < 2; ++db) {
#pragma unroll
      for (int rq = 0; rq < 4; ++rq) {
        const int sq = 8 * T32 + 2 * rq + h;   // t-quad (4 consecutive t)
        uint2 vr = Vb2[(((size_t)(bh * 32 + (sq >> 4)) * 4 + ((sq >> 2) & 3)) * 2 + db) * 128
                       + l31 * 4 + ((sq >> 1) & 1) * 2 + (sq & 1)];
        float vres[4];
        vres[0] = bf2f((ushort)(vr.x & 0xFFFFu));
        vres[1] = bf2f((ushort)(vr.x >> 16));
        vres[2] = bf2f((ushort)(vr.y & 0xFFFFu));
        vres[3] = bf2f((ushort)(vr.y >> 16));
#pragma unroll
        for (int rr = 0; rr < 4; ++rr) {
          const int row = rr + 8 * rq + 4 * h;          // t-local in [0,32)
          const float iT = __shfl(inv, row, 64);
          const int t = T32 * 32 + row;
          out[((size_t)(b * T_SEQ + t)) * EMB + hh * D_H + db * 32 + l31] =
              oacc[tb][db][rq * 4 + rr] * iT + vres[rr];
        }
      }
    }
  }
}

extern "C" void kernel_launch(void* const* d_in, const int* in_sizes, int n_in,
                              void* d_out, int out_size, void* d_ws, size_t ws_size,
                              hipStream_t stream) {
  const float* x  = (const float*)d_in[0];
  const float* Wq = (const float*)d_in[1];
  const float* Wk = (const float*)d_in[2];
  const float* Wv = (const float*)d_in[3];
  float* out = (float*)d_out;

  const size_t per4 = (size_t)64 * 64 * 4 * 64;  // 1,048,576 uint4 per blob (16 MB)
  uint4* Qb = (uint4*)d_ws;
  uint4* Kb = Qb + per4;
  uint4* Vb = Kb + per4;
  ushort* Wb = (ushort*)(Vb + per4);  // 24 KB of bf16 W fragments
  // ws needed: 3 * 16.78 MB + 24 KB = 50.4 MB

  wconv<<<1, 64, 0, stream>>>(Wq, Wk, Wv, Wb);
  proj_qkv<<<2048, 256, 0, stream>>>(x, Wb, (uint2*)Qb, (uint2*)Kb, (uint2*)Vb);
  attn_fused<<<512, 256, 0, stream>>>(Qb, Kb, Vb, out);
}